// Round 13
// baseline (196.044 us; speedup 1.0000x reference)
//
#include <hip/hip_runtime.h>
#include <math.h>

#define NN 100000
#define DI 64
#define DH 128
#define DO 40

#define NPB 64           // nodes per bucket == agg block rows (power of 2!)
#define NBUCK 1563       // ceil(100000/64)
#define CAP 1408         // bucket capacity: Poisson(1024) + 12 sigma
#define COLCAP 1856      // CAP + 64*7 pad slack (x8 padding)
#define EPB 4096         // edges per scatter block
#define TPB_S 512        // threads per scatter/setup block
#define KE (EPB / TPB_S) // edges per thread = 8

typedef __attribute__((ext_vector_type(8))) short bf16x8;
typedef __attribute__((ext_vector_type(4))) float f32x4;
typedef __attribute__((ext_vector_type(2))) float f32x2;

__device__ __forceinline__ unsigned short bf16r(float a) {
    unsigned u = __float_as_uint(a);
    u = (u + 0x7FFF + ((u >> 16) & 1)) >> 16;
    return (unsigned short)u;
}
__device__ __forceinline__ unsigned bf16pair(float a, float b) {
    return (unsigned)bf16r(a) | ((unsigned)bf16r(b) << 16);
}
__device__ __forceinline__ float bflo(unsigned u) { return __uint_as_float(u << 16); }
__device__ __forceinline__ float bfhi(unsigned u) { return __uint_as_float(u & 0xFFFF0000u); }

// ---------- fused: scatter blocks [0,nbe) + setup blocks [nbe, nbe+nsetup) ----------
// Buckets are now 64 nodes (bucket = d>>6): shift not magic-div; LDS hist 1563 ints.
__global__ __launch_bounds__(TPB_S) void setup_scatter_kernel(
        const float* __restrict__ x, const float* __restrict__ W1l,
        const float* __restrict__ W1r, const float* __restrict__ W2l,
        const float* __restrict__ W2r,
        unsigned* __restrict__ xb, unsigned short* __restrict__ xgs,
        unsigned short* __restrict__ WB1,
        unsigned short* __restrict__ WB2, unsigned* __restrict__ p2,
        const int* __restrict__ src, const int* __restrict__ dst,
        int* __restrict__ bcur, int* __restrict__ eb,
        int nbe, int E, int N) {
    __shared__ int h[NBUCK];
    int t = threadIdx.x;
    if ((int)blockIdx.x < nbe) {
        // ---- bucket scatter: eb[pos] = (local<<17)|src ----
        for (int i = t; i < NBUCK; i += TPB_S) h[i] = 0;
        __syncthreads();
        int base = blockIdx.x * EPB;
        int end = base + EPB; if (end > E) end = E;
        int dloc[KE];
#pragma unroll
        for (int k = 0; k < KE; k++) {
            int i = base + t + k * TPB_S;
            dloc[k] = (i < end) ? dst[i] : -1;
        }
#pragma unroll
        for (int k = 0; k < KE; k++)
            if (dloc[k] >= 0) atomicAdd(&h[(unsigned)dloc[k] >> 6], 1);
        __syncthreads();
        for (int i = t; i < NBUCK; i += TPB_S) {
            int v = h[i];
            h[i] = v ? (atomicAdd(&bcur[i], v) + i * CAP) : 0;
        }
        __syncthreads();
#pragma unroll
        for (int k = 0; k < KE; k++) {
            int d = dloc[k];
            if (d >= 0) {
                unsigned bk = (unsigned)d >> 6;
                int local = d & 63;
                int pos = atomicAdd(&h[bk], 1);
                eb[pos] = (local << 17) | src[base + t + k * TPB_S];
            }
        }
    } else {
        // ---- setup: x->bf16 + x->fp8 gather copy, weight packs, p2 dummy row ----
        int idx = (blockIdx.x - nbe) * TPB_S + t;
        if (idx < (N + 1) * 32) {
            if (idx < N * 32) {
                float2 f = ((const float2*)x)[idx];
                xb[idx] = bf16pair(f.x, f.y);
                xgs[idx] = (unsigned short)
                    __builtin_amdgcn_cvt_pk_fp8_f32(f.x, f.y, 0u, false);
            } else {
                xb[idx] = 0;          // dummy row N (bf16)
                xgs[idx] = 0;         // dummy row N (fp8 -> 0.0)
            }
        }
        if (idx < 16384) {
            int j = idx & 7, lane = (idx >> 3) & 63, ks = (idx >> 9) & 3, nt = idx >> 11;
            int k = ks * 32 + (lane >> 4) * 8 + j;
            int n = nt * 16 + (lane & 15);
            float v = (k < DI) ? W1l[n * DI + k] : W1r[n * DI + (k - DI)];
            WB1[idx] = bf16r(v);
        }
        if (idx >= 16384 && idx < 16384 + 10240) {
            int idx2 = idx - 16384;
            int j = idx2 & 7, lane = (idx2 >> 3) & 63, ks = (idx2 >> 9) & 3, nt = idx2 >> 11;
            int k = ks * 32 + (lane >> 4) * 8 + j;
            int n = nt * 16 + (lane & 15);
            float v = (n < DO) ? W2l[n * DH + k] : W2r[(n - DO) * DH + k];
            WB2[idx2] = bf16r(v);
        }
        if (idx < 10) p2[(size_t)N * 10 + idx] = 0;   // dummy fp8 row N (decodes to 0)
    }
}

// ---------- fused SORT + agg1 + GEMM1 + GEMM2: block == bucket (64 nodes) ----------
// In-block: eb segment -> count(64 bins) -> wave0 prefix -> LDS col_l scatter ->
// pads -> coalesced colg copy (for agg2) + rowptr/cnt/inv writes.
// Then the proven round-12 pipeline, Phase A reading col from LDS.
__global__ __launch_bounds__(256) void agg_gemm12_kernel(
        const unsigned* __restrict__ xb, const unsigned short* __restrict__ xgs,
        const int* __restrict__ eb, const int* __restrict__ bend,
        int* __restrict__ rowptr, int* __restrict__ cntg, float* __restrict__ invg,
        int* __restrict__ colg,
        const unsigned short* __restrict__ WB1, const float* __restrict__ b1,
        const unsigned short* __restrict__ WB2, const float* __restrict__ b2,
        unsigned* __restrict__ p2, unsigned short* __restrict__ selfpb, int N) {
    __shared__ unsigned short sh[64][136];        // A-tile -> h-tile -> f32 stage
    __shared__ __align__(16) int col_l[COLCAP];   // per-node edge lists (padded x8)
    __shared__ int scnt[64], sbase[64], scur[64];
    __shared__ int stot;
    int t = threadIdx.x;
    int b = blockIdx.x;
    int cnt_b = bend[b];                          // bucket edge count
    size_t ebeg = (size_t)b * CAP;

    // ---- sort phase ----
    if (t < 64) scnt[t] = 0;
    __syncthreads();
    for (int i = t; i < cnt_b; i += 256)
        atomicAdd(&scnt[eb[ebeg + i] >> 17], 1);
    __syncthreads();
    if (t < 64) {                                 // wave 0: shuffle prefix scan
        int c = scnt[t];
        int pc = (c + 7) & ~7;                    // pad to x8 (agg2 reads 8-wide)
        int scan = pc;
#pragma unroll
        for (int off = 1; off < 64; off <<= 1) {
            int u = __shfl_up(scan, off);
            if (t >= off) scan += u;
        }
        int base = scan - pc;
        sbase[t] = base;
        scur[t] = base;
        if (t == 63) stot = scan;
        int node = b * 64 + t;
        if (node < N) {
            rowptr[node] = b * COLCAP + base;
            cntg[node] = c;
            invg[node] = 1.0f / (float)(c > 0 ? c : 1);
        }
    }
    __syncthreads();
    for (int i = t; i < cnt_b; i += 256) {
        int pk = eb[ebeg + i];
        int pos = atomicAdd(&scur[pk >> 17], 1);
        col_l[pos] = pk & 0x1FFFF;
    }
    __syncthreads();
    if (t < 64) {
        int c = scnt[t], pc = (c + 7) & ~7, base = sbase[t];
        for (int i = c; i < pc; i++) col_l[base + i] = NN;   // pads -> zero dummy row
    }
    __syncthreads();
    {   // coalesced copy for agg2 (col_l is final; Phase A also reads it below)
        int tot = stot;
        for (int i = t; i < tot; i += 256)
            colg[(size_t)b * COLCAP + i] = col_l[i];
    }

    // ---- Phase A: aggregate wave-private rows (fp8 gather, col from LDS) ----
    int w = t >> 6, lane = t & 63;
    int lw = w * 16;
    int g8 = (t >> 3) & 7;                   // gather group within wave: 0..7
    int chunk = t & 7;                       // 8B fp8 chunk within row
    int rbase = b * 64 + lw;
#pragma unroll
    for (int it = 0; it < 2; ++it) {
        int lr = lw + g8 + it * 8;
        int n = b * 64 + lr;
        bool valid = (n < N);
        int ne = valid ? n : NN;             // NN = zero dummy row
        float a[8];
#pragma unroll
        for (int j = 0; j < 8; j++) a[j] = 0.f;
        float invn = 0.f;
        if (valid) {
            int beg = sbase[lr], deg = scnt[lr];
            int degp = (deg + 3) & ~3;
            for (int i = 0; i < degp; i += 4) {
                int4 c4 = *(const int4*)(col_l + beg + i);
                uint2 g0 = *(const uint2*)(xgs + (size_t)c4.x * 32 + chunk * 4);
                uint2 g1 = *(const uint2*)(xgs + (size_t)c4.y * 32 + chunk * 4);
                uint2 g2 = *(const uint2*)(xgs + (size_t)c4.z * 32 + chunk * 4);
                uint2 g3 = *(const uint2*)(xgs + (size_t)c4.w * 32 + chunk * 4);
                f32x2 d;
                d = __builtin_amdgcn_cvt_pk_f32_fp8(g0.x, false); a[0] += d.x; a[1] += d.y;
                d = __builtin_amdgcn_cvt_pk_f32_fp8(g0.x, true);  a[2] += d.x; a[3] += d.y;
                d = __builtin_amdgcn_cvt_pk_f32_fp8(g0.y, false); a[4] += d.x; a[5] += d.y;
                d = __builtin_amdgcn_cvt_pk_f32_fp8(g0.y, true);  a[6] += d.x; a[7] += d.y;
                d = __builtin_amdgcn_cvt_pk_f32_fp8(g1.x, false); a[0] += d.x; a[1] += d.y;
                d = __builtin_amdgcn_cvt_pk_f32_fp8(g1.x, true);  a[2] += d.x; a[3] += d.y;
                d = __builtin_amdgcn_cvt_pk_f32_fp8(g1.y, false); a[4] += d.x; a[5] += d.y;
                d = __builtin_amdgcn_cvt_pk_f32_fp8(g1.y, true);  a[6] += d.x; a[7] += d.y;
                d = __builtin_amdgcn_cvt_pk_f32_fp8(g2.x, false); a[0] += d.x; a[1] += d.y;
                d = __builtin_amdgcn_cvt_pk_f32_fp8(g2.x, true);  a[2] += d.x; a[3] += d.y;
                d = __builtin_amdgcn_cvt_pk_f32_fp8(g2.y, false); a[4] += d.x; a[5] += d.y;
                d = __builtin_amdgcn_cvt_pk_f32_fp8(g2.y, true);  a[6] += d.x; a[7] += d.y;
                d = __builtin_amdgcn_cvt_pk_f32_fp8(g3.x, false); a[0] += d.x; a[1] += d.y;
                d = __builtin_amdgcn_cvt_pk_f32_fp8(g3.x, true);  a[2] += d.x; a[3] += d.y;
                d = __builtin_amdgcn_cvt_pk_f32_fp8(g3.y, false); a[4] += d.x; a[5] += d.y;
                d = __builtin_amdgcn_cvt_pk_f32_fp8(g3.y, true);  a[6] += d.x; a[7] += d.y;
            }
            invn = 1.0f / (float)(deg > 0 ? deg : 1);
        }
        // self features stay bf16 (exact path)
        uint4 u = *(const uint4*)(xb + (size_t)ne * 32 + chunk * 4);
        uint4 o;
        o.x = bf16pair(a[0] * invn, a[1] * invn);
        o.y = bf16pair(a[2] * invn, a[3] * invn);
        o.z = bf16pair(a[4] * invn, a[5] * invn);
        o.w = bf16pair(a[6] * invn, a[7] * invn);
        *(uint4*)&sh[lr][chunk * 8] = o;        // agg half (cols 0..63)
        *(uint4*)&sh[lr][64 + chunk * 8] = u;   // self half (cols 64..127)
    }
    asm volatile("" ::: "memory");

    // ---- Phase B: GEMM1 (reads/writes only own rows) ----
    int quad = lane >> 4, m = lane & 15;
    f32x4 acc[8];
#pragma unroll
    for (int nt = 0; nt < 8; nt++) acc[nt] = (f32x4)(0.f);
#pragma unroll
    for (int ks = 0; ks < 4; ks++) {
        bf16x8 a = *(const bf16x8*)(&sh[lw + m][ks * 32 + quad * 8]);
#pragma unroll
        for (int nt = 0; nt < 8; nt++) {
            bf16x8 bb = *(const bf16x8*)(WB1 + ((size_t)(nt * 4 + ks) * 64 + lane) * 8);
            acc[nt] = __builtin_amdgcn_mfma_f32_16x16x32_bf16(a, bb, acc[nt], 0, 0, 0);
        }
    }
    asm volatile("" ::: "memory");
#pragma unroll
    for (int nt = 0; nt < 8; nt++) {
        int colj = nt * 16 + m;
        float bj = b1[colj];
#pragma unroll
        for (int r = 0; r < 4; r++) {
            sh[lw + quad * 4 + r][colj] = bf16r(fmaxf(acc[nt][r] + bj, 0.f));
        }
    }
    asm volatile("" ::: "memory");

    // ---- Phase C: GEMM2 ----
    f32x4 acc2[5];
#pragma unroll
    for (int nt = 0; nt < 5; nt++) acc2[nt] = (f32x4)(0.f);
#pragma unroll
    for (int ks = 0; ks < 4; ks++) {
        bf16x8 a = *(const bf16x8*)(&sh[lw + m][ks * 32 + quad * 8]);
#pragma unroll
        for (int nt = 0; nt < 5; nt++) {
            bf16x8 bb = *(const bf16x8*)(WB2 + ((size_t)(nt * 4 + ks) * 64 + lane) * 8);
            acc2[nt] = __builtin_amdgcn_mfma_f32_16x16x32_bf16(a, bb, acc2[nt], 0, 0, 0);
        }
    }
    asm volatile("" ::: "memory");
    float* stw = (float*)&sh[lw][0];         // 16 rows x 41 f32 = 2624 B <= 4352 B
#pragma unroll
    for (int nt = 0; nt < 5; nt++) {
        int colj = nt * 16 + m;
#pragma unroll
        for (int r = 0; r < 4; r++) {
            int row = rbase + quad * 4 + r;
            float v = acc2[nt][r];
            if (colj < 40) {
                stw[(quad * 4 + r) * 41 + colj] = v;
            } else if (row < N) {
                selfpb[(size_t)row * 40 + (colj - 40)] = bf16r(v + b2[colj - 40]);
            }
        }
    }
    asm volatile("" ::: "memory");
    for (int i = lane; i < 160; i += 64) {
        int lr = i / 10, dw = i - lr * 10;
        int grow = rbase + lr;
        if (grow < N) {
            float v0 = stw[lr * 41 + dw * 4 + 0], v1 = stw[lr * 41 + dw * 4 + 1];
            float v2 = stw[lr * 41 + dw * 4 + 2], v3 = stw[lr * 41 + dw * 4 + 3];
            unsigned u = __builtin_amdgcn_cvt_pk_fp8_f32(v0, v1, 0u, false);
            u = __builtin_amdgcn_cvt_pk_fp8_f32(v2, v3, u, true);
            p2[(size_t)grow * 10 + dw] = u;
        }
    }
}

// ---------- agg2 + log_softmax: 8 lanes/node (5 active), edges 8-wide ----------
// (unchanged; reads colg via absolute rowptr)
__global__ void agg2_softmax_kernel(const unsigned* __restrict__ p2,
                                    const unsigned short* __restrict__ selfpb,
                                    const int* __restrict__ rowptr,
                                    const int* __restrict__ cnt,
                                    const float* __restrict__ inv,
                                    const int* __restrict__ col,
                                    float* __restrict__ out, int N) {
    int n = (blockIdx.x * 256 + threadIdx.x) >> 3;
    int chunk = threadIdx.x & 7;
    if (n >= N) return;
    int beg = rowptr[n], deg = cnt[n];
    int degp = (deg + 7) & ~7;
    bool vc = (chunk < 5);
    float a[8];
#pragma unroll
    for (int j = 0; j < 8; j++) a[j] = 0.f;
    for (int i = 0; i < degp; i += 8) {
        int ss[8];
#pragma unroll
        for (int k = 0; k < 8; k++) ss[k] = col[beg + i + k];
        if (vc) {
            uint2 uu[8];
#pragma unroll
            for (int k = 0; k < 8; k++)
                uu[k] = *(const uint2*)(p2 + (size_t)ss[k] * 10 + chunk * 2);
#pragma unroll
            for (int k = 0; k < 8; k++) {
                f32x2 d;
                d = __builtin_amdgcn_cvt_pk_f32_fp8(uu[k].x, false); a[0] += d.x; a[1] += d.y;
                d = __builtin_amdgcn_cvt_pk_f32_fp8(uu[k].x, true);  a[2] += d.x; a[3] += d.y;
                d = __builtin_amdgcn_cvt_pk_f32_fp8(uu[k].y, false); a[4] += d.x; a[5] += d.y;
                d = __builtin_amdgcn_cvt_pk_f32_fp8(uu[k].y, true);  a[6] += d.x; a[7] += d.y;
            }
        }
    }
    float invn = inv[n];
    float v[8];
    if (vc) {
        uint4 sv = *(const uint4*)(selfpb + (size_t)n * 40 + chunk * 8);
        v[0] = a[0] * invn + bflo(sv.x); v[1] = a[1] * invn + bfhi(sv.x);
        v[2] = a[2] * invn + bflo(sv.y); v[3] = a[3] * invn + bfhi(sv.y);
        v[4] = a[4] * invn + bflo(sv.z); v[5] = a[5] * invn + bfhi(sv.z);
        v[6] = a[6] * invn + bflo(sv.w); v[7] = a[7] * invn + bfhi(sv.w);
    } else {
#pragma unroll
        for (int j = 0; j < 8; j++) v[j] = 0.f;
    }
    float mv = -INFINITY;
    if (vc) {
#pragma unroll
        for (int j = 0; j < 8; j++) mv = fmaxf(mv, v[j]);
    }
#pragma unroll
    for (int off = 1; off <= 4; off <<= 1) mv = fmaxf(mv, __shfl_xor(mv, off, 8));
    float es = 0.f;
    if (vc) {
#pragma unroll
        for (int j = 0; j < 8; j++) es += expf(v[j] - mv);
    }
#pragma unroll
    for (int off = 1; off <= 4; off <<= 1) es += __shfl_xor(es, off, 8);
    if (vc) {
        float ls = mv + logf(es);
        float4 o0, o1;
        o0.x = v[0] - ls; o0.y = v[1] - ls; o0.z = v[2] - ls; o0.w = v[3] - ls;
        o1.x = v[4] - ls; o1.y = v[5] - ls; o1.z = v[6] - ls; o1.w = v[7] - ls;
        *(float4*)(out + (size_t)n * DO + chunk * 8) = o0;
        *(float4*)(out + (size_t)n * DO + chunk * 8 + 4) = o1;
    }
}

extern "C" void kernel_launch(void* const* d_in, const int* in_sizes, int n_in,
                              void* d_out, int out_size, void* d_ws, size_t ws_size,
                              hipStream_t stream) {
    const float* x   = (const float*)d_in[0];
    const int*  ei   = (const int*)d_in[1];
    const float* W1l = (const float*)d_in[2];
    const float* b1  = (const float*)d_in[3];
    const float* W1r = (const float*)d_in[4];
    const float* W2l = (const float*)d_in[5];
    const float* b2  = (const float*)d_in[6];
    const float* W2r = (const float*)d_in[7];
    float* out = (float*)d_out;

    const int E = in_sizes[1] / 2;
    const int N = NN;
    const int* src = ei;
    const int* dst = ei + E;
    const int nbe = (E + EPB - 1) / EPB;
    const int nsetup = ((N + 1) * 32 + TPB_S - 1) / TPB_S;

    size_t off = 0;
    auto alloc = [&](size_t nf) { size_t o = off; off += (nf + 63) & ~(size_t)63; return o; };
    size_t o_bcur   = alloc(NBUCK);                      // int (counts, memset to 0)
    size_t o_eb     = alloc((size_t)NBUCK * CAP);        // int (bucket-clustered edges)
    size_t o_colg   = alloc((size_t)NBUCK * COLCAP + 64);// int (padded CSR col, for agg2)
    size_t o_rowptr = alloc(N);                          // int
    size_t o_cnt    = alloc(N);                          // int
    size_t o_inv    = alloc(N);                          // f32
    size_t o_xb     = alloc((size_t)(N + 1) * 32);       // u32 (64 bf16/row, +dummy)
    size_t o_xg     = alloc((size_t)(N + 1) * 16);       // fp8 x64/row = 64B (+dummy)
    size_t o_p2     = alloc((size_t)(N + 1) * 10);       // u32 (40 fp8/row, +dummy)
    size_t o_selfp  = alloc((size_t)N * 20);             // bf16 x40/row = 80B
    size_t o_wb1    = alloc(16384 / 2);
    size_t o_wb2    = alloc(10240 / 2);
    (void)ws_size;

    float* ws = (float*)d_ws;
    int* bcur   = (int*)(ws + o_bcur);
    int* eb     = (int*)(ws + o_eb);
    int* colg   = (int*)(ws + o_colg);
    int* rowptr = (int*)(ws + o_rowptr);
    int* cnt    = (int*)(ws + o_cnt);
    float* inv  = ws + o_inv;
    unsigned* xb = (unsigned*)(ws + o_xb);
    unsigned short* xgs = (unsigned short*)(ws + o_xg);
    unsigned* p2 = (unsigned*)(ws + o_p2);
    unsigned short* selfpb = (unsigned short*)(ws + o_selfp);
    unsigned short* WB1 = (unsigned short*)(ws + o_wb1);
    unsigned short* WB2 = (unsigned short*)(ws + o_wb2);

    hipMemsetAsync(bcur, 0, NBUCK * sizeof(int), stream);

    setup_scatter_kernel<<<nbe + nsetup, TPB_S, 0, stream>>>(
        x, W1l, W1r, W2l, W2r, xb, xgs, WB1, WB2, p2, src, dst, bcur, eb, nbe, E, N);

    agg_gemm12_kernel<<<NBUCK, 256, 0, stream>>>(
        xb, xgs, eb, bcur, rowptr, cnt, inv, colg,
        WB1, b1, WB2, b2, p2, selfpb, N);

    agg2_softmax_kernel<<<(N * 8 + 255) / 256, 256, 0, stream>>>(
        p2, selfpb, rowptr, cnt, inv, colg, out, N);
}

// Round 14
// 193.752 us; speedup vs baseline: 1.0118x; 1.0118x over previous
//
#include <hip/hip_runtime.h>
#include <math.h>

#define NN 100000
#define DI 64
#define DH 128
#define DO 40

#define NPB_C 256        // nodes per COARSE bucket (setup scatter granularity)
#define NBUCK_C 391      // ceil(100000/256)
#define CAP_C 4608       // coarse bucket capacity: Poisson(4096) + 8 sigma
#define COLCAP 1856      // per-agg-block (64-node) col capacity incl. x8 padding
#define EPB 4096         // edges per scatter block
#define TPB_S 512        // threads per scatter/setup block
#define KE (EPB / TPB_S) // edges per thread = 8

typedef __attribute__((ext_vector_type(8))) short bf16x8;
typedef __attribute__((ext_vector_type(4))) float f32x4;
typedef __attribute__((ext_vector_type(2))) float f32x2;

__device__ __forceinline__ unsigned short bf16r(float a) {
    unsigned u = __float_as_uint(a);
    u = (u + 0x7FFF + ((u >> 16) & 1)) >> 16;
    return (unsigned short)u;
}
__device__ __forceinline__ unsigned bf16pair(float a, float b) {
    return (unsigned)bf16r(a) | ((unsigned)bf16r(b) << 16);
}
__device__ __forceinline__ float bflo(unsigned u) { return __uint_as_float(u << 16); }
__device__ __forceinline__ float bfhi(unsigned u) { return __uint_as_float(u & 0xFFFF0000u); }

// ---------- fused: scatter blocks [0,nbe) + setup blocks [nbe, nbe+nsetup) ----------
// COARSE buckets (256 nodes, d>>8): 10.5 edges/bucket/block -> contiguous ~42B
// runs per write region -> low line amplification (the r12-proven regime).
__global__ __launch_bounds__(TPB_S) void setup_scatter_kernel(
        const float* __restrict__ x, const float* __restrict__ W1l,
        const float* __restrict__ W1r, const float* __restrict__ W2l,
        const float* __restrict__ W2r,
        unsigned* __restrict__ xb, unsigned short* __restrict__ xgs,
        unsigned short* __restrict__ WB1,
        unsigned short* __restrict__ WB2, unsigned* __restrict__ p2,
        const int* __restrict__ src, const int* __restrict__ dst,
        int* __restrict__ bcur, int* __restrict__ eb,
        int nbe, int E, int N) {
    __shared__ int h[NBUCK_C];
    int t = threadIdx.x;
    if ((int)blockIdx.x < nbe) {
        // ---- bucket scatter: eb[pos] = (local<<17)|src, local = d & 255 ----
        if (t < NBUCK_C) h[t] = 0;
        __syncthreads();
        int base = blockIdx.x * EPB;
        int end = base + EPB; if (end > E) end = E;
        int dloc[KE];
#pragma unroll
        for (int k = 0; k < KE; k++) {
            int i = base + t + k * TPB_S;
            dloc[k] = (i < end) ? dst[i] : -1;
        }
#pragma unroll
        for (int k = 0; k < KE; k++)
            if (dloc[k] >= 0) atomicAdd(&h[(unsigned)dloc[k] >> 8], 1);
        __syncthreads();
        if (t < NBUCK_C) {
            int v = h[t];
            h[t] = v ? (atomicAdd(&bcur[t], v) + t * CAP_C) : 0;
        }
        __syncthreads();
#pragma unroll
        for (int k = 0; k < KE; k++) {
            int d = dloc[k];
            if (d >= 0) {
                unsigned bk = (unsigned)d >> 8;
                int local = d & 255;
                int pos = atomicAdd(&h[bk], 1);
                eb[pos] = (local << 17) | src[base + t + k * TPB_S];
            }
        }
    } else {
        // ---- setup: x->bf16 + x->fp8 gather copy, weight packs, p2 dummy row ----
        int idx = (blockIdx.x - nbe) * TPB_S + t;
        if (idx < (N + 1) * 32) {
            if (idx < N * 32) {
                float2 f = ((const float2*)x)[idx];
                xb[idx] = bf16pair(f.x, f.y);
                xgs[idx] = (unsigned short)
                    __builtin_amdgcn_cvt_pk_fp8_f32(f.x, f.y, 0u, false);
            } else {
                xb[idx] = 0;          // dummy row N (bf16)
                xgs[idx] = 0;         // dummy row N (fp8 -> 0.0)
            }
        }
        if (idx < 16384) {
            int j = idx & 7, lane = (idx >> 3) & 63, ks = (idx >> 9) & 3, nt = idx >> 11;
            int k = ks * 32 + (lane >> 4) * 8 + j;
            int n = nt * 16 + (lane & 15);
            float v = (k < DI) ? W1l[n * DI + k] : W1r[n * DI + (k - DI)];
            WB1[idx] = bf16r(v);
        }
        if (idx >= 16384 && idx < 16384 + 10240) {
            int idx2 = idx - 16384;
            int j = idx2 & 7, lane = (idx2 >> 3) & 63, ks = (idx2 >> 9) & 3, nt = idx2 >> 11;
            int k = ks * 32 + (lane >> 4) * 8 + j;
            int n = nt * 16 + (lane & 15);
            float v = (n < DO) ? W2l[n * DH + k] : W2r[(n - DO) * DH + k];
            WB2[idx2] = bf16r(v);
        }
        if (idx < 10) p2[(size_t)N * 10 + idx] = 0;   // dummy fp8 row N (decodes to 0)
    }
}

// ---------- fused SORT + agg1 + GEMM1 + GEMM2: agg block = quarter of a coarse bucket ----------
// Block b: coarse bucket cb=b>>2, quarter sub=b&3. Scans the coarse eb segment,
// filters (local>>6)==sub, sorts its 64 nodes into LDS col_l (free under gather
// latency, proven r13), then the proven r12 pipeline with col from LDS.
__global__ __launch_bounds__(256) void agg_gemm12_kernel(
        const unsigned* __restrict__ xb, const unsigned short* __restrict__ xgs,
        const int* __restrict__ eb, const int* __restrict__ bend,
        int* __restrict__ rowptr, int* __restrict__ cntg, float* __restrict__ invg,
        int* __restrict__ colg,
        const unsigned short* __restrict__ WB1, const float* __restrict__ b1,
        const unsigned short* __restrict__ WB2, const float* __restrict__ b2,
        unsigned* __restrict__ p2, unsigned short* __restrict__ selfpb, int N) {
    __shared__ unsigned short sh[64][136];        // A-tile -> h-tile -> f32 stage
    __shared__ __align__(16) int col_l[COLCAP];   // per-node edge lists (padded x8)
    __shared__ int scnt[64], sbase[64], scur[64];
    __shared__ int stot;
    int t = threadIdx.x;
    int b = blockIdx.x;
    int cb = b >> 2, sub = b & 3;
    int cnt_b = bend[cb];                         // coarse bucket edge count
    size_t ebeg = (size_t)cb * CAP_C;

    // ---- sort phase (filtered scan of the coarse segment) ----
    if (t < 64) scnt[t] = 0;
    __syncthreads();
    for (int i = t; i < cnt_b; i += 256) {
        int loc = eb[ebeg + i] >> 17;
        if ((loc >> 6) == sub) atomicAdd(&scnt[loc & 63], 1);
    }
    __syncthreads();
    if (t < 64) {                                 // wave 0: shuffle prefix scan
        int c = scnt[t];
        int pc = (c + 7) & ~7;                    // pad to x8 (agg2 reads 8-wide)
        int scan = pc;
#pragma unroll
        for (int off = 1; off < 64; off <<= 1) {
            int u = __shfl_up(scan, off);
            if (t >= off) scan += u;
        }
        int base = scan - pc;
        sbase[t] = base;
        scur[t] = base;
        if (t == 63) stot = scan;
        int node = b * 64 + t;
        if (node < N) {
            rowptr[node] = b * COLCAP + base;
            cntg[node] = c;
            invg[node] = 1.0f / (float)(c > 0 ? c : 1);
        }
    }
    __syncthreads();
    for (int i = t; i < cnt_b; i += 256) {
        int pk = eb[ebeg + i];
        int loc = pk >> 17;
        if ((loc >> 6) == sub) {
            int pos = atomicAdd(&scur[loc & 63], 1);
            col_l[pos] = pk & 0x1FFFF;
        }
    }
    __syncthreads();
    if (t < 64) {
        int c = scnt[t], pc = (c + 7) & ~7, base = sbase[t];
        for (int i = c; i < pc; i++) col_l[base + i] = NN;   // pads -> zero dummy row
    }
    __syncthreads();
    {   // coalesced copy for agg2 (col_l is final; Phase A also reads it below)
        int tot = stot;
        for (int i = t; i < tot; i += 256)
            colg[(size_t)b * COLCAP + i] = col_l[i];
    }

    // ---- Phase A: aggregate wave-private rows (fp8 gather, col from LDS) ----
    int w = t >> 6, lane = t & 63;
    int lw = w * 16;
    int g8 = (t >> 3) & 7;                   // gather group within wave: 0..7
    int chunk = t & 7;                       // 8B fp8 chunk within row
    int rbase = b * 64 + lw;
#pragma unroll
    for (int it = 0; it < 2; ++it) {
        int lr = lw + g8 + it * 8;
        int n = b * 64 + lr;
        bool valid = (n < N);
        int ne = valid ? n : NN;             // NN = zero dummy row
        float a[8];
#pragma unroll
        for (int j = 0; j < 8; j++) a[j] = 0.f;
        float invn = 0.f;
        if (valid) {
            int beg = sbase[lr], deg = scnt[lr];
            int degp = (deg + 3) & ~3;
            for (int i = 0; i < degp; i += 4) {
                int4 c4 = *(const int4*)(col_l + beg + i);
                uint2 g0 = *(const uint2*)(xgs + (size_t)c4.x * 32 + chunk * 4);
                uint2 g1 = *(const uint2*)(xgs + (size_t)c4.y * 32 + chunk * 4);
                uint2 g2 = *(const uint2*)(xgs + (size_t)c4.z * 32 + chunk * 4);
                uint2 g3 = *(const uint2*)(xgs + (size_t)c4.w * 32 + chunk * 4);
                f32x2 d;
                d = __builtin_amdgcn_cvt_pk_f32_fp8(g0.x, false); a[0] += d.x; a[1] += d.y;
                d = __builtin_amdgcn_cvt_pk_f32_fp8(g0.x, true);  a[2] += d.x; a[3] += d.y;
                d = __builtin_amdgcn_cvt_pk_f32_fp8(g0.y, false); a[4] += d.x; a[5] += d.y;
                d = __builtin_amdgcn_cvt_pk_f32_fp8(g0.y, true);  a[6] += d.x; a[7] += d.y;
                d = __builtin_amdgcn_cvt_pk_f32_fp8(g1.x, false); a[0] += d.x; a[1] += d.y;
                d = __builtin_amdgcn_cvt_pk_f32_fp8(g1.x, true);  a[2] += d.x; a[3] += d.y;
                d = __builtin_amdgcn_cvt_pk_f32_fp8(g1.y, false); a[4] += d.x; a[5] += d.y;
                d = __builtin_amdgcn_cvt_pk_f32_fp8(g1.y, true);  a[6] += d.x; a[7] += d.y;
                d = __builtin_amdgcn_cvt_pk_f32_fp8(g2.x, false); a[0] += d.x; a[1] += d.y;
                d = __builtin_amdgcn_cvt_pk_f32_fp8(g2.x, true);  a[2] += d.x; a[3] += d.y;
                d = __builtin_amdgcn_cvt_pk_f32_fp8(g2.y, false); a[4] += d.x; a[5] += d.y;
                d = __builtin_amdgcn_cvt_pk_f32_fp8(g2.y, true);  a[6] += d.x; a[7] += d.y;
                d = __builtin_amdgcn_cvt_pk_f32_fp8(g3.x, false); a[0] += d.x; a[1] += d.y;
                d = __builtin_amdgcn_cvt_pk_f32_fp8(g3.x, true);  a[2] += d.x; a[3] += d.y;
                d = __builtin_amdgcn_cvt_pk_f32_fp8(g3.y, false); a[4] += d.x; a[5] += d.y;
                d = __builtin_amdgcn_cvt_pk_f32_fp8(g3.y, true);  a[6] += d.x; a[7] += d.y;
            }
            invn = 1.0f / (float)(deg > 0 ? deg : 1);
        }
        // self features stay bf16 (exact path)
        uint4 u = *(const uint4*)(xb + (size_t)ne * 32 + chunk * 4);
        uint4 o;
        o.x = bf16pair(a[0] * invn, a[1] * invn);
        o.y = bf16pair(a[2] * invn, a[3] * invn);
        o.z = bf16pair(a[4] * invn, a[5] * invn);
        o.w = bf16pair(a[6] * invn, a[7] * invn);
        *(uint4*)&sh[lr][chunk * 8] = o;        // agg half (cols 0..63)
        *(uint4*)&sh[lr][64 + chunk * 8] = u;   // self half (cols 64..127)
    }
    asm volatile("" ::: "memory");

    // ---- Phase B: GEMM1 (reads/writes only own rows) ----
    int quad = lane >> 4, m = lane & 15;
    f32x4 acc[8];
#pragma unroll
    for (int nt = 0; nt < 8; nt++) acc[nt] = (f32x4)(0.f);
#pragma unroll
    for (int ks = 0; ks < 4; ks++) {
        bf16x8 a = *(const bf16x8*)(&sh[lw + m][ks * 32 + quad * 8]);
#pragma unroll
        for (int nt = 0; nt < 8; nt++) {
            bf16x8 bb = *(const bf16x8*)(WB1 + ((size_t)(nt * 4 + ks) * 64 + lane) * 8);
            acc[nt] = __builtin_amdgcn_mfma_f32_16x16x32_bf16(a, bb, acc[nt], 0, 0, 0);
        }
    }
    asm volatile("" ::: "memory");
#pragma unroll
    for (int nt = 0; nt < 8; nt++) {
        int colj = nt * 16 + m;
        float bj = b1[colj];
#pragma unroll
        for (int r = 0; r < 4; r++) {
            sh[lw + quad * 4 + r][colj] = bf16r(fmaxf(acc[nt][r] + bj, 0.f));
        }
    }
    asm volatile("" ::: "memory");

    // ---- Phase C: GEMM2 ----
    f32x4 acc2[5];
#pragma unroll
    for (int nt = 0; nt < 5; nt++) acc2[nt] = (f32x4)(0.f);
#pragma unroll
    for (int ks = 0; ks < 4; ks++) {
        bf16x8 a = *(const bf16x8*)(&sh[lw + m][ks * 32 + quad * 8]);
#pragma unroll
        for (int nt = 0; nt < 5; nt++) {
            bf16x8 bb = *(const bf16x8*)(WB2 + ((size_t)(nt * 4 + ks) * 64 + lane) * 8);
            acc2[nt] = __builtin_amdgcn_mfma_f32_16x16x32_bf16(a, bb, acc2[nt], 0, 0, 0);
        }
    }
    asm volatile("" ::: "memory");
    float* stw = (float*)&sh[lw][0];         // 16 rows x 41 f32 = 2624 B <= 4352 B
#pragma unroll
    for (int nt = 0; nt < 5; nt++) {
        int colj = nt * 16 + m;
#pragma unroll
        for (int r = 0; r < 4; r++) {
            int row = rbase + quad * 4 + r;
            float v = acc2[nt][r];
            if (colj < 40) {
                stw[(quad * 4 + r) * 41 + colj] = v;
            } else if (row < N) {
                selfpb[(size_t)row * 40 + (colj - 40)] = bf16r(v + b2[colj - 40]);
            }
        }
    }
    asm volatile("" ::: "memory");
    for (int i = lane; i < 160; i += 64) {
        int lr = i / 10, dw = i - lr * 10;
        int grow = rbase + lr;
        if (grow < N) {
            float v0 = stw[lr * 41 + dw * 4 + 0], v1 = stw[lr * 41 + dw * 4 + 1];
            float v2 = stw[lr * 41 + dw * 4 + 2], v3 = stw[lr * 41 + dw * 4 + 3];
            unsigned u = __builtin_amdgcn_cvt_pk_fp8_f32(v0, v1, 0u, false);
            u = __builtin_amdgcn_cvt_pk_fp8_f32(v2, v3, u, true);
            p2[(size_t)grow * 10 + dw] = u;
        }
    }
}

// ---------- agg2 + log_softmax: 8 lanes/node (5 active), edges 8-wide ----------
// (unchanged; reads colg via absolute rowptr)
__global__ void agg2_softmax_kernel(const unsigned* __restrict__ p2,
                                    const unsigned short* __restrict__ selfpb,
                                    const int* __restrict__ rowptr,
                                    const int* __restrict__ cnt,
                                    const float* __restrict__ inv,
                                    const int* __restrict__ col,
                                    float* __restrict__ out, int N) {
    int n = (blockIdx.x * 256 + threadIdx.x) >> 3;
    int chunk = threadIdx.x & 7;
    if (n >= N) return;
    int beg = rowptr[n], deg = cnt[n];
    int degp = (deg + 7) & ~7;
    bool vc = (chunk < 5);
    float a[8];
#pragma unroll
    for (int j = 0; j < 8; j++) a[j] = 0.f;
    for (int i = 0; i < degp; i += 8) {
        int ss[8];
#pragma unroll
        for (int k = 0; k < 8; k++) ss[k] = col[beg + i + k];
        if (vc) {
            uint2 uu[8];
#pragma unroll
            for (int k = 0; k < 8; k++)
                uu[k] = *(const uint2*)(p2 + (size_t)ss[k] * 10 + chunk * 2);
#pragma unroll
            for (int k = 0; k < 8; k++) {
                f32x2 d;
                d = __builtin_amdgcn_cvt_pk_f32_fp8(uu[k].x, false); a[0] += d.x; a[1] += d.y;
                d = __builtin_amdgcn_cvt_pk_f32_fp8(uu[k].x, true);  a[2] += d.x; a[3] += d.y;
                d = __builtin_amdgcn_cvt_pk_f32_fp8(uu[k].y, false); a[4] += d.x; a[5] += d.y;
                d = __builtin_amdgcn_cvt_pk_f32_fp8(uu[k].y, true);  a[6] += d.x; a[7] += d.y;
            }
        }
    }
    float invn = inv[n];
    float v[8];
    if (vc) {
        uint4 sv = *(const uint4*)(selfpb + (size_t)n * 40 + chunk * 8);
        v[0] = a[0] * invn + bflo(sv.x); v[1] = a[1] * invn + bfhi(sv.x);
        v[2] = a[2] * invn + bflo(sv.y); v[3] = a[3] * invn + bfhi(sv.y);
        v[4] = a[4] * invn + bflo(sv.z); v[5] = a[5] * invn + bfhi(sv.z);
        v[6] = a[6] * invn + bflo(sv.w); v[7] = a[7] * invn + bfhi(sv.w);
    } else {
#pragma unroll
        for (int j = 0; j < 8; j++) v[j] = 0.f;
    }
    float mv = -INFINITY;
    if (vc) {
#pragma unroll
        for (int j = 0; j < 8; j++) mv = fmaxf(mv, v[j]);
    }
#pragma unroll
    for (int off = 1; off <= 4; off <<= 1) mv = fmaxf(mv, __shfl_xor(mv, off, 8));
    float es = 0.f;
    if (vc) {
#pragma unroll
        for (int j = 0; j < 8; j++) es += expf(v[j] - mv);
    }
#pragma unroll
    for (int off = 1; off <= 4; off <<= 1) es += __shfl_xor(es, off, 8);
    if (vc) {
        float ls = mv + logf(es);
        float4 o0, o1;
        o0.x = v[0] - ls; o0.y = v[1] - ls; o0.z = v[2] - ls; o0.w = v[3] - ls;
        o1.x = v[4] - ls; o1.y = v[5] - ls; o1.z = v[6] - ls; o1.w = v[7] - ls;
        *(float4*)(out + (size_t)n * DO + chunk * 8) = o0;
        *(float4*)(out + (size_t)n * DO + chunk * 8 + 4) = o1;
    }
}

extern "C" void kernel_launch(void* const* d_in, const int* in_sizes, int n_in,
                              void* d_out, int out_size, void* d_ws, size_t ws_size,
                              hipStream_t stream) {
    const float* x   = (const float*)d_in[0];
    const int*  ei   = (const int*)d_in[1];
    const float* W1l = (const float*)d_in[2];
    const float* b1  = (const float*)d_in[3];
    const float* W1r = (const float*)d_in[4];
    const float* W2l = (const float*)d_in[5];
    const float* b2  = (const float*)d_in[6];
    const float* W2r = (const float*)d_in[7];
    float* out = (float*)d_out;

    const int E = in_sizes[1] / 2;
    const int N = NN;
    const int* src = ei;
    const int* dst = ei + E;
    const int nbe = (E + EPB - 1) / EPB;
    const int nsetup = ((N + 1) * 32 + TPB_S - 1) / TPB_S;
    const int nagg = (N + 63) / 64;    // 1563 agg blocks = 4 per coarse bucket

    size_t off = 0;
    auto alloc = [&](size_t nf) { size_t o = off; off += (nf + 63) & ~(size_t)63; return o; };
    size_t o_bcur   = alloc(NBUCK_C);                     // int (counts, memset to 0)
    size_t o_eb     = alloc((size_t)NBUCK_C * CAP_C);     // int (coarse-clustered edges)
    size_t o_colg   = alloc((size_t)nagg * COLCAP + 64);  // int (padded CSR col, for agg2)
    size_t o_rowptr = alloc(N);                           // int
    size_t o_cnt    = alloc(N);                           // int
    size_t o_inv    = alloc(N);                           // f32
    size_t o_xb     = alloc((size_t)(N + 1) * 32);        // u32 (64 bf16/row, +dummy)
    size_t o_xg     = alloc((size_t)(N + 1) * 16);        // fp8 x64/row = 64B (+dummy)
    size_t o_p2     = alloc((size_t)(N + 1) * 10);        // u32 (40 fp8/row, +dummy)
    size_t o_selfp  = alloc((size_t)N * 20);              // bf16 x40/row = 80B
    size_t o_wb1    = alloc(16384 / 2);
    size_t o_wb2    = alloc(10240 / 2);
    (void)ws_size;

    float* ws = (float*)d_ws;
    int* bcur   = (int*)(ws + o_bcur);
    int* eb     = (int*)(ws + o_eb);
    int* colg   = (int*)(ws + o_colg);
    int* rowptr = (int*)(ws + o_rowptr);
    int* cnt    = (int*)(ws + o_cnt);
    float* inv  = ws + o_inv;
    unsigned* xb = (unsigned*)(ws + o_xb);
    unsigned short* xgs = (unsigned short*)(ws + o_xg);
    unsigned* p2 = (unsigned*)(ws + o_p2);
    unsigned short* selfpb = (unsigned short*)(ws + o_selfp);
    unsigned short* WB1 = (unsigned short*)(ws + o_wb1);
    unsigned short* WB2 = (unsigned short*)(ws + o_wb2);

    hipMemsetAsync(bcur, 0, NBUCK_C * sizeof(int), stream);

    setup_scatter_kernel<<<nbe + nsetup, TPB_S, 0, stream>>>(
        x, W1l, W1r, W2l, W2r, xb, xgs, WB1, WB2, p2, src, dst, bcur, eb, nbe, E, N);

    agg_gemm12_kernel<<<nagg, 256, 0, stream>>>(
        xb, xgs, eb, bcur, rowptr, cnt, inv, colg,
        WB1, b1, WB2, b2, p2, selfpb, N);

    agg2_softmax_kernel<<<(N * 8 + 255) / 256, 256, 0, stream>>>(
        p2, selfpb, rowptr, cnt, inv, colg, out, N);
}

// Round 15
// 186.902 us; speedup vs baseline: 1.0489x; 1.0366x over previous
//
#include <hip/hip_runtime.h>
#include <math.h>

#define NN 100000
#define DI 64
#define DH 128
#define DO 40

#define NPB_C 128        // nodes per COARSE bucket (setup scatter granularity)
#define NBUCK_C 782      // ceil(100000/128)
#define CAP_C 2560       // coarse bucket capacity: Poisson(2048) + 11 sigma
#define COLCAP 1856      // per-agg-block (64-node) col capacity incl. x8 padding
#define EPB 4096         // edges per scatter block
#define TPB_S 512        // threads per scatter/setup block
#define KE (EPB / TPB_S) // edges per thread = 8
#define KE2 10           // agg sort: eb segment regs/thread (2560/256)

typedef __attribute__((ext_vector_type(8))) short bf16x8;
typedef __attribute__((ext_vector_type(4))) float f32x4;
typedef __attribute__((ext_vector_type(2))) float f32x2;

__device__ __forceinline__ unsigned short bf16r(float a) {
    unsigned u = __float_as_uint(a);
    u = (u + 0x7FFF + ((u >> 16) & 1)) >> 16;
    return (unsigned short)u;
}
__device__ __forceinline__ unsigned bf16pair(float a, float b) {
    return (unsigned)bf16r(a) | ((unsigned)bf16r(b) << 16);
}
__device__ __forceinline__ float bflo(unsigned u) { return __uint_as_float(u << 16); }
__device__ __forceinline__ float bfhi(unsigned u) { return __uint_as_float(u & 0xFFFF0000u); }

// ---------- fused: scatter blocks [0,nbe) + setup blocks [nbe, nbe+nsetup) ----------
// 128-node coarse buckets (d>>7): 5.2 edges/bucket/block -> ~21B runs -> ~2.5x amp.
__global__ __launch_bounds__(TPB_S) void setup_scatter_kernel(
        const float* __restrict__ x, const float* __restrict__ W1l,
        const float* __restrict__ W1r, const float* __restrict__ W2l,
        const float* __restrict__ W2r,
        unsigned* __restrict__ xb, unsigned short* __restrict__ xgs,
        unsigned short* __restrict__ WB1,
        unsigned short* __restrict__ WB2, unsigned* __restrict__ p2,
        const int* __restrict__ src, const int* __restrict__ dst,
        int* __restrict__ bcur, int* __restrict__ eb,
        int nbe, int E, int N) {
    __shared__ int h[NBUCK_C];
    int t = threadIdx.x;
    if ((int)blockIdx.x < nbe) {
        // ---- bucket scatter: eb[pos] = (local<<17)|src, local = d & 127 ----
        for (int i = t; i < NBUCK_C; i += TPB_S) h[i] = 0;
        __syncthreads();
        int base = blockIdx.x * EPB;
        int end = base + EPB; if (end > E) end = E;
        int dloc[KE];
#pragma unroll
        for (int k = 0; k < KE; k++) {
            int i = base + t + k * TPB_S;
            dloc[k] = (i < end) ? dst[i] : -1;
        }
#pragma unroll
        for (int k = 0; k < KE; k++)
            if (dloc[k] >= 0) atomicAdd(&h[(unsigned)dloc[k] >> 7], 1);
        __syncthreads();
        for (int i = t; i < NBUCK_C; i += TPB_S) {
            int v = h[i];
            h[i] = v ? (atomicAdd(&bcur[i], v) + i * CAP_C) : 0;
        }
        __syncthreads();
#pragma unroll
        for (int k = 0; k < KE; k++) {
            int d = dloc[k];
            if (d >= 0) {
                unsigned bk = (unsigned)d >> 7;
                int local = d & 127;
                int pos = atomicAdd(&h[bk], 1);
                eb[pos] = (local << 17) | src[base + t + k * TPB_S];
            }
        }
    } else {
        // ---- setup: x->bf16 + x->fp8 gather copy, weight packs, p2 dummy row ----
        int idx = (blockIdx.x - nbe) * TPB_S + t;
        if (idx < (N + 1) * 32) {
            if (idx < N * 32) {
                float2 f = ((const float2*)x)[idx];
                xb[idx] = bf16pair(f.x, f.y);
                xgs[idx] = (unsigned short)
                    __builtin_amdgcn_cvt_pk_fp8_f32(f.x, f.y, 0u, false);
            } else {
                xb[idx] = 0;          // dummy row N (bf16)
                xgs[idx] = 0;         // dummy row N (fp8 -> 0.0)
            }
        }
        if (idx < 16384) {
            int j = idx & 7, lane = (idx >> 3) & 63, ks = (idx >> 9) & 3, nt = idx >> 11;
            int k = ks * 32 + (lane >> 4) * 8 + j;
            int n = nt * 16 + (lane & 15);
            float v = (k < DI) ? W1l[n * DI + k] : W1r[n * DI + (k - DI)];
            WB1[idx] = bf16r(v);
        }
        if (idx >= 16384 && idx < 16384 + 10240) {
            int idx2 = idx - 16384;
            int j = idx2 & 7, lane = (idx2 >> 3) & 63, ks = (idx2 >> 9) & 3, nt = idx2 >> 11;
            int k = ks * 32 + (lane >> 4) * 8 + j;
            int n = nt * 16 + (lane & 15);
            float v = (n < DO) ? W2l[n * DH + k] : W2r[(n - DO) * DH + k];
            WB2[idx2] = bf16r(v);
        }
        if (idx < 10) p2[(size_t)N * 10 + idx] = 0;   // dummy fp8 row N (decodes to 0)
    }
}

// ---------- fused SORT + agg1 + GEMM1 + GEMM2: agg block = half a coarse bucket ----------
// Block b: coarse bucket cb=b>>1, half sub=b&1. Loads the coarse segment ONCE into
// registers (<=10/thread), counts + scatters its half from regs, then the proven
// r12 pipeline with col from LDS.
__global__ __launch_bounds__(256) void agg_gemm12_kernel(
        const unsigned* __restrict__ xb, const unsigned short* __restrict__ xgs,
        const int* __restrict__ eb, const int* __restrict__ bend,
        int* __restrict__ rowptr, int* __restrict__ cntg, float* __restrict__ invg,
        int* __restrict__ colg,
        const unsigned short* __restrict__ WB1, const float* __restrict__ b1,
        const unsigned short* __restrict__ WB2, const float* __restrict__ b2,
        unsigned* __restrict__ p2, unsigned short* __restrict__ selfpb, int N) {
    __shared__ unsigned short sh[64][136];        // A-tile -> h-tile -> f32 stage
    __shared__ __align__(16) int col_l[COLCAP];   // per-node edge lists (padded x8)
    __shared__ int scnt[64], sbase[64], scur[64];
    __shared__ int stot;
    int t = threadIdx.x;
    int b = blockIdx.x;
    int cb = b >> 1, sub = b & 1;
    int cnt_b = bend[cb];                         // coarse bucket edge count
    size_t ebeg = (size_t)cb * CAP_C;

    // ---- sort phase: register-cached single scan of the coarse segment ----
    int ec[KE2];
#pragma unroll
    for (int j = 0; j < KE2; j++) {
        int i = t + j * 256;
        ec[j] = (i < cnt_b) ? eb[ebeg + i] : -1;
    }
    if (t < 64) scnt[t] = 0;
    __syncthreads();
#pragma unroll
    for (int j = 0; j < KE2; j++) {
        int pk = ec[j];
        if (pk >= 0) {
            int loc = pk >> 17;                   // 7 bits: 0..127
            if ((loc >> 6) == sub) atomicAdd(&scnt[loc & 63], 1);
        }
    }
    __syncthreads();
    if (t < 64) {                                 // wave 0: shuffle prefix scan
        int c = scnt[t];
        int pc = (c + 7) & ~7;                    // pad to x8 (agg2 reads 8-wide)
        int scan = pc;
#pragma unroll
        for (int off = 1; off < 64; off <<= 1) {
            int u = __shfl_up(scan, off);
            if (t >= off) scan += u;
        }
        int base = scan - pc;
        sbase[t] = base;
        scur[t] = base;
        if (t == 63) stot = scan;
        int node = b * 64 + t;
        if (node < N) {
            rowptr[node] = b * COLCAP + base;
            cntg[node] = c;
            invg[node] = 1.0f / (float)(c > 0 ? c : 1);
        }
    }
    __syncthreads();
#pragma unroll
    for (int j = 0; j < KE2; j++) {
        int pk = ec[j];
        if (pk >= 0) {
            int loc = pk >> 17;
            if ((loc >> 6) == sub) {
                int pos = atomicAdd(&scur[loc & 63], 1);
                col_l[pos] = pk & 0x1FFFF;
            }
        }
    }
    __syncthreads();
    if (t < 64) {
        int c = scnt[t], pc = (c + 7) & ~7, base = sbase[t];
        for (int i = c; i < pc; i++) col_l[base + i] = NN;   // pads -> zero dummy row
    }
    __syncthreads();
    {   // coalesced copy for agg2 (col_l is final; Phase A also reads it below)
        int tot = stot;
        for (int i = t; i < tot; i += 256)
            colg[(size_t)b * COLCAP + i] = col_l[i];
    }

    // ---- Phase A: aggregate wave-private rows (fp8 gather, col from LDS) ----
    int w = t >> 6, lane = t & 63;
    int lw = w * 16;
    int g8 = (t >> 3) & 7;                   // gather group within wave: 0..7
    int chunk = t & 7;                       // 8B fp8 chunk within row
    int rbase = b * 64 + lw;
#pragma unroll
    for (int it = 0; it < 2; ++it) {
        int lr = lw + g8 + it * 8;
        int n = b * 64 + lr;
        bool valid = (n < N);
        int ne = valid ? n : NN;             // NN = zero dummy row
        float a[8];
#pragma unroll
        for (int j = 0; j < 8; j++) a[j] = 0.f;
        float invn = 0.f;
        if (valid) {
            int beg = sbase[lr], deg = scnt[lr];
            int degp = (deg + 3) & ~3;
            for (int i = 0; i < degp; i += 4) {
                int4 c4 = *(const int4*)(col_l + beg + i);
                uint2 g0 = *(const uint2*)(xgs + (size_t)c4.x * 32 + chunk * 4);
                uint2 g1 = *(const uint2*)(xgs + (size_t)c4.y * 32 + chunk * 4);
                uint2 g2 = *(const uint2*)(xgs + (size_t)c4.z * 32 + chunk * 4);
                uint2 g3 = *(const uint2*)(xgs + (size_t)c4.w * 32 + chunk * 4);
                f32x2 d;
                d = __builtin_amdgcn_cvt_pk_f32_fp8(g0.x, false); a[0] += d.x; a[1] += d.y;
                d = __builtin_amdgcn_cvt_pk_f32_fp8(g0.x, true);  a[2] += d.x; a[3] += d.y;
                d = __builtin_amdgcn_cvt_pk_f32_fp8(g0.y, false); a[4] += d.x; a[5] += d.y;
                d = __builtin_amdgcn_cvt_pk_f32_fp8(g0.y, true);  a[6] += d.x; a[7] += d.y;
                d = __builtin_amdgcn_cvt_pk_f32_fp8(g1.x, false); a[0] += d.x; a[1] += d.y;
                d = __builtin_amdgcn_cvt_pk_f32_fp8(g1.x, true);  a[2] += d.x; a[3] += d.y;
                d = __builtin_amdgcn_cvt_pk_f32_fp8(g1.y, false); a[4] += d.x; a[5] += d.y;
                d = __builtin_amdgcn_cvt_pk_f32_fp8(g1.y, true);  a[6] += d.x; a[7] += d.y;
                d = __builtin_amdgcn_cvt_pk_f32_fp8(g2.x, false); a[0] += d.x; a[1] += d.y;
                d = __builtin_amdgcn_cvt_pk_f32_fp8(g2.x, true);  a[2] += d.x; a[3] += d.y;
                d = __builtin_amdgcn_cvt_pk_f32_fp8(g2.y, false); a[4] += d.x; a[5] += d.y;
                d = __builtin_amdgcn_cvt_pk_f32_fp8(g2.y, true);  a[6] += d.x; a[7] += d.y;
                d = __builtin_amdgcn_cvt_pk_f32_fp8(g3.x, false); a[0] += d.x; a[1] += d.y;
                d = __builtin_amdgcn_cvt_pk_f32_fp8(g3.x, true);  a[2] += d.x; a[3] += d.y;
                d = __builtin_amdgcn_cvt_pk_f32_fp8(g3.y, false); a[4] += d.x; a[5] += d.y;
                d = __builtin_amdgcn_cvt_pk_f32_fp8(g3.y, true);  a[6] += d.x; a[7] += d.y;
            }
            invn = 1.0f / (float)(deg > 0 ? deg : 1);
        }
        // self features stay bf16 (exact path)
        uint4 u = *(const uint4*)(xb + (size_t)ne * 32 + chunk * 4);
        uint4 o;
        o.x = bf16pair(a[0] * invn, a[1] * invn);
        o.y = bf16pair(a[2] * invn, a[3] * invn);
        o.z = bf16pair(a[4] * invn, a[5] * invn);
        o.w = bf16pair(a[6] * invn, a[7] * invn);
        *(uint4*)&sh[lr][chunk * 8] = o;        // agg half (cols 0..63)
        *(uint4*)&sh[lr][64 + chunk * 8] = u;   // self half (cols 64..127)
    }
    asm volatile("" ::: "memory");

    // ---- Phase B: GEMM1 (reads/writes only own rows) ----
    int quad = lane >> 4, m = lane & 15;
    f32x4 acc[8];
#pragma unroll
    for (int nt = 0; nt < 8; nt++) acc[nt] = (f32x4)(0.f);
#pragma unroll
    for (int ks = 0; ks < 4; ks++) {
        bf16x8 a = *(const bf16x8*)(&sh[lw + m][ks * 32 + quad * 8]);
#pragma unroll
        for (int nt = 0; nt < 8; nt++) {
            bf16x8 bb = *(const bf16x8*)(WB1 + ((size_t)(nt * 4 + ks) * 64 + lane) * 8);
            acc[nt] = __builtin_amdgcn_mfma_f32_16x16x32_bf16(a, bb, acc[nt], 0, 0, 0);
        }
    }
    asm volatile("" ::: "memory");
#pragma unroll
    for (int nt = 0; nt < 8; nt++) {
        int colj = nt * 16 + m;
        float bj = b1[colj];
#pragma unroll
        for (int r = 0; r < 4; r++) {
            sh[lw + quad * 4 + r][colj] = bf16r(fmaxf(acc[nt][r] + bj, 0.f));
        }
    }
    asm volatile("" ::: "memory");

    // ---- Phase C: GEMM2 ----
    f32x4 acc2[5];
#pragma unroll
    for (int nt = 0; nt < 5; nt++) acc2[nt] = (f32x4)(0.f);
#pragma unroll
    for (int ks = 0; ks < 4; ks++) {
        bf16x8 a = *(const bf16x8*)(&sh[lw + m][ks * 32 + quad * 8]);
#pragma unroll
        for (int nt = 0; nt < 5; nt++) {
            bf16x8 bb = *(const bf16x8*)(WB2 + ((size_t)(nt * 4 + ks) * 64 + lane) * 8);
            acc2[nt] = __builtin_amdgcn_mfma_f32_16x16x32_bf16(a, bb, acc2[nt], 0, 0, 0);
        }
    }
    asm volatile("" ::: "memory");
    float* stw = (float*)&sh[lw][0];         // 16 rows x 41 f32 = 2624 B <= 4352 B
#pragma unroll
    for (int nt = 0; nt < 5; nt++) {
        int colj = nt * 16 + m;
#pragma unroll
        for (int r = 0; r < 4; r++) {
            int row = rbase + quad * 4 + r;
            float v = acc2[nt][r];
            if (colj < 40) {
                stw[(quad * 4 + r) * 41 + colj] = v;
            } else if (row < N) {
                selfpb[(size_t)row * 40 + (colj - 40)] = bf16r(v + b2[colj - 40]);
            }
        }
    }
    asm volatile("" ::: "memory");
    for (int i = lane; i < 160; i += 64) {
        int lr = i / 10, dw = i - lr * 10;
        int grow = rbase + lr;
        if (grow < N) {
            float v0 = stw[lr * 41 + dw * 4 + 0], v1 = stw[lr * 41 + dw * 4 + 1];
            float v2 = stw[lr * 41 + dw * 4 + 2], v3 = stw[lr * 41 + dw * 4 + 3];
            unsigned u = __builtin_amdgcn_cvt_pk_fp8_f32(v0, v1, 0u, false);
            u = __builtin_amdgcn_cvt_pk_fp8_f32(v2, v3, u, true);
            p2[(size_t)grow * 10 + dw] = u;
        }
    }
}

// ---------- agg2 + log_softmax: 8 lanes/node (5 active), edges 8-wide ----------
// (unchanged; reads colg via absolute rowptr)
__global__ void agg2_softmax_kernel(const unsigned* __restrict__ p2,
                                    const unsigned short* __restrict__ selfpb,
                                    const int* __restrict__ rowptr,
                                    const int* __restrict__ cnt,
                                    const float* __restrict__ inv,
                                    const int* __restrict__ col,
                                    float* __restrict__ out, int N) {
    int n = (blockIdx.x * 256 + threadIdx.x) >> 3;
    int chunk = threadIdx.x & 7;
    if (n >= N) return;
    int beg = rowptr[n], deg = cnt[n];
    int degp = (deg + 7) & ~7;
    bool vc = (chunk < 5);
    float a[8];
#pragma unroll
    for (int j = 0; j < 8; j++) a[j] = 0.f;
    for (int i = 0; i < degp; i += 8) {
        int ss[8];
#pragma unroll
        for (int k = 0; k < 8; k++) ss[k] = col[beg + i + k];
        if (vc) {
            uint2 uu[8];
#pragma unroll
            for (int k = 0; k < 8; k++)
                uu[k] = *(const uint2*)(p2 + (size_t)ss[k] * 10 + chunk * 2);
#pragma unroll
            for (int k = 0; k < 8; k++) {
                f32x2 d;
                d = __builtin_amdgcn_cvt_pk_f32_fp8(uu[k].x, false); a[0] += d.x; a[1] += d.y;
                d = __builtin_amdgcn_cvt_pk_f32_fp8(uu[k].x, true);  a[2] += d.x; a[3] += d.y;
                d = __builtin_amdgcn_cvt_pk_f32_fp8(uu[k].y, false); a[4] += d.x; a[5] += d.y;
                d = __builtin_amdgcn_cvt_pk_f32_fp8(uu[k].y, true);  a[6] += d.x; a[7] += d.y;
            }
        }
    }
    float invn = inv[n];
    float v[8];
    if (vc) {
        uint4 sv = *(const uint4*)(selfpb + (size_t)n * 40 + chunk * 8);
        v[0] = a[0] * invn + bflo(sv.x); v[1] = a[1] * invn + bfhi(sv.x);
        v[2] = a[2] * invn + bflo(sv.y); v[3] = a[3] * invn + bfhi(sv.y);
        v[4] = a[4] * invn + bflo(sv.z); v[5] = a[5] * invn + bfhi(sv.z);
        v[6] = a[6] * invn + bflo(sv.w); v[7] = a[7] * invn + bfhi(sv.w);
    } else {
#pragma unroll
        for (int j = 0; j < 8; j++) v[j] = 0.f;
    }
    float mv = -INFINITY;
    if (vc) {
#pragma unroll
        for (int j = 0; j < 8; j++) mv = fmaxf(mv, v[j]);
    }
#pragma unroll
    for (int off = 1; off <= 4; off <<= 1) mv = fmaxf(mv, __shfl_xor(mv, off, 8));
    float es = 0.f;
    if (vc) {
#pragma unroll
        for (int j = 0; j < 8; j++) es += expf(v[j] - mv);
    }
#pragma unroll
    for (int off = 1; off <= 4; off <<= 1) es += __shfl_xor(es, off, 8);
    if (vc) {
        float ls = mv + logf(es);
        float4 o0, o1;
        o0.x = v[0] - ls; o0.y = v[1] - ls; o0.z = v[2] - ls; o0.w = v[3] - ls;
        o1.x = v[4] - ls; o1.y = v[5] - ls; o1.z = v[6] - ls; o1.w = v[7] - ls;
        *(float4*)(out + (size_t)n * DO + chunk * 8) = o0;
        *(float4*)(out + (size_t)n * DO + chunk * 8 + 4) = o1;
    }
}

extern "C" void kernel_launch(void* const* d_in, const int* in_sizes, int n_in,
                              void* d_out, int out_size, void* d_ws, size_t ws_size,
                              hipStream_t stream) {
    const float* x   = (const float*)d_in[0];
    const int*  ei   = (const int*)d_in[1];
    const float* W1l = (const float*)d_in[2];
    const float* b1  = (const float*)d_in[3];
    const float* W1r = (const float*)d_in[4];
    const float* W2l = (const float*)d_in[5];
    const float* b2  = (const float*)d_in[6];
    const float* W2r = (const float*)d_in[7];
    float* out = (float*)d_out;

    const int E = in_sizes[1] / 2;
    const int N = NN;
    const int* src = ei;
    const int* dst = ei + E;
    const int nbe = (E + EPB - 1) / EPB;
    const int nsetup = ((N + 1) * 32 + TPB_S - 1) / TPB_S;
    const int nagg = (N + 63) / 64;    // 1563 agg blocks = 2 per coarse bucket

    size_t off = 0;
    auto alloc = [&](size_t nf) { size_t o = off; off += (nf + 63) & ~(size_t)63; return o; };
    size_t o_bcur   = alloc(NBUCK_C);                     // int (counts, memset to 0)
    size_t o_eb     = alloc((size_t)NBUCK_C * CAP_C);     // int (coarse-clustered edges)
    size_t o_colg   = alloc((size_t)nagg * COLCAP + 64);  // int (padded CSR col, for agg2)
    size_t o_rowptr = alloc(N);                           // int
    size_t o_cnt    = alloc(N);                           // int
    size_t o_inv    = alloc(N);                           // f32
    size_t o_xb     = alloc((size_t)(N + 1) * 32);        // u32 (64 bf16/row, +dummy)
    size_t o_xg     = alloc((size_t)(N + 1) * 16);        // fp8 x64/row = 64B (+dummy)
    size_t o_p2     = alloc((size_t)(N + 1) * 10);        // u32 (40 fp8/row, +dummy)
    size_t o_selfp  = alloc((size_t)N * 20);              // bf16 x40/row = 80B
    size_t o_wb1    = alloc(16384 / 2);
    size_t o_wb2    = alloc(10240 / 2);
    (void)ws_size;

    float* ws = (float*)d_ws;
    int* bcur   = (int*)(ws + o_bcur);
    int* eb     = (int*)(ws + o_eb);
    int* colg   = (int*)(ws + o_colg);
    int* rowptr = (int*)(ws + o_rowptr);
    int* cnt    = (int*)(ws + o_cnt);
    float* inv  = ws + o_inv;
    unsigned* xb = (unsigned*)(ws + o_xb);
    unsigned short* xgs = (unsigned short*)(ws + o_xg);
    unsigned* p2 = (unsigned*)(ws + o_p2);
    unsigned short* selfpb = (unsigned short*)(ws + o_selfp);
    unsigned short* WB1 = (unsigned short*)(ws + o_wb1);
    unsigned short* WB2 = (unsigned short*)(ws + o_wb2);

    hipMemsetAsync(bcur, 0, NBUCK_C * sizeof(int), stream);

    setup_scatter_kernel<<<nbe + nsetup, TPB_S, 0, stream>>>(
        x, W1l, W1r, W2l, W2r, xb, xgs, WB1, WB2, p2, src, dst, bcur, eb, nbe, E, N);

    agg_gemm12_kernel<<<nagg, 256, 0, stream>>>(
        xb, xgs, eb, bcur, rowptr, cnt, inv, colg,
        WB1, b1, WB2, b2, p2, selfpb, N);

    agg2_softmax_kernel<<<(N * 8 + 255) / 256, 256, 0, stream>>>(
        p2, selfpb, rowptr, cnt, inv, colg, out, N);
}

// Round 16
// 185.642 us; speedup vs baseline: 1.0560x; 1.0068x over previous
//
#include <hip/hip_runtime.h>
#include <math.h>

#define NN 100000
#define DI 64
#define DH 128
#define DO 40

#define NPB_C 128        // nodes per COARSE bucket (setup scatter granularity)
#define NBUCK_C 782      // ceil(100000/128)
#define CAP_C 2560       // coarse bucket capacity: Poisson(2048) + 11 sigma
#define COLCAP 1856      // per-agg-block (64-node) col capacity incl. x8 padding
#define EPB 4096         // edges per scatter block
#define TPB_S 512        // threads per scatter/setup block
#define KE (EPB / TPB_S) // edges per thread = 8
#define KE2 10           // agg sort: eb segment regs/thread (2560/256)
#define P2S 16           // p2 row stride in u32 (64B = one cache line, padded)

typedef __attribute__((ext_vector_type(8))) short bf16x8;
typedef __attribute__((ext_vector_type(4))) float f32x4;
typedef __attribute__((ext_vector_type(2))) float f32x2;

__device__ __forceinline__ unsigned short bf16r(float a) {
    unsigned u = __float_as_uint(a);
    u = (u + 0x7FFF + ((u >> 16) & 1)) >> 16;
    return (unsigned short)u;
}
__device__ __forceinline__ unsigned bf16pair(float a, float b) {
    return (unsigned)bf16r(a) | ((unsigned)bf16r(b) << 16);
}
__device__ __forceinline__ float bflo(unsigned u) { return __uint_as_float(u << 16); }
__device__ __forceinline__ float bfhi(unsigned u) { return __uint_as_float(u & 0xFFFF0000u); }

// ---------- fused: scatter blocks [0,nbe) + setup blocks [nbe, nbe+nsetup) ----------
// 128-node coarse buckets (d>>7): 5.2 edges/bucket/block -> ~21B runs -> ~2.5x amp.
__global__ __launch_bounds__(TPB_S) void setup_scatter_kernel(
        const float* __restrict__ x, const float* __restrict__ W1l,
        const float* __restrict__ W1r, const float* __restrict__ W2l,
        const float* __restrict__ W2r,
        unsigned* __restrict__ xb, unsigned short* __restrict__ xgs,
        unsigned short* __restrict__ WB1,
        unsigned short* __restrict__ WB2, unsigned* __restrict__ p2,
        const int* __restrict__ src, const int* __restrict__ dst,
        int* __restrict__ bcur, int* __restrict__ eb,
        int nbe, int E, int N) {
    __shared__ int h[NBUCK_C];
    int t = threadIdx.x;
    if ((int)blockIdx.x < nbe) {
        // ---- bucket scatter: eb[pos] = (local<<17)|src, local = d & 127 ----
        for (int i = t; i < NBUCK_C; i += TPB_S) h[i] = 0;
        __syncthreads();
        int base = blockIdx.x * EPB;
        int end = base + EPB; if (end > E) end = E;
        int dloc[KE];
#pragma unroll
        for (int k = 0; k < KE; k++) {
            int i = base + t + k * TPB_S;
            dloc[k] = (i < end) ? dst[i] : -1;
        }
#pragma unroll
        for (int k = 0; k < KE; k++)
            if (dloc[k] >= 0) atomicAdd(&h[(unsigned)dloc[k] >> 7], 1);
        __syncthreads();
        for (int i = t; i < NBUCK_C; i += TPB_S) {
            int v = h[i];
            h[i] = v ? (atomicAdd(&bcur[i], v) + i * CAP_C) : 0;
        }
        __syncthreads();
#pragma unroll
        for (int k = 0; k < KE; k++) {
            int d = dloc[k];
            if (d >= 0) {
                unsigned bk = (unsigned)d >> 7;
                int local = d & 127;
                int pos = atomicAdd(&h[bk], 1);
                eb[pos] = (local << 17) | src[base + t + k * TPB_S];
            }
        }
    } else {
        // ---- setup: x->bf16 + x->fp8 gather copy, weight packs, p2 dummy row ----
        int idx = (blockIdx.x - nbe) * TPB_S + t;
        if (idx < (N + 1) * 32) {
            if (idx < N * 32) {
                float2 f = ((const float2*)x)[idx];
                xb[idx] = bf16pair(f.x, f.y);
                xgs[idx] = (unsigned short)
                    __builtin_amdgcn_cvt_pk_fp8_f32(f.x, f.y, 0u, false);
            } else {
                xb[idx] = 0;          // dummy row N (bf16)
                xgs[idx] = 0;         // dummy row N (fp8 -> 0.0)
            }
        }
        if (idx < 16384) {
            int j = idx & 7, lane = (idx >> 3) & 63, ks = (idx >> 9) & 3, nt = idx >> 11;
            int k = ks * 32 + (lane >> 4) * 8 + j;
            int n = nt * 16 + (lane & 15);
            float v = (k < DI) ? W1l[n * DI + k] : W1r[n * DI + (k - DI)];
            WB1[idx] = bf16r(v);
        }
        if (idx >= 16384 && idx < 16384 + 10240) {
            int idx2 = idx - 16384;
            int j = idx2 & 7, lane = (idx2 >> 3) & 63, ks = (idx2 >> 9) & 3, nt = idx2 >> 11;
            int k = ks * 32 + (lane >> 4) * 8 + j;
            int n = nt * 16 + (lane & 15);
            float v = (n < DO) ? W2l[n * DH + k] : W2r[(n - DO) * DH + k];
            WB2[idx2] = bf16r(v);
        }
        if (idx < 10) p2[(size_t)N * P2S + idx] = 0;  // dummy fp8 row N (decodes to 0)
    }
}

// ---------- fused SORT + agg1 + GEMM1 + GEMM2: agg block = half a coarse bucket ----------
// Block b: coarse bucket cb=b>>1, half sub=b&1. Loads the coarse segment ONCE into
// registers (<=10/thread), counts + scatters its half from regs, then the proven
// r12 pipeline with col from LDS.
__global__ __launch_bounds__(256) void agg_gemm12_kernel(
        const unsigned* __restrict__ xb, const unsigned short* __restrict__ xgs,
        const int* __restrict__ eb, const int* __restrict__ bend,
        int* __restrict__ rowptr, int* __restrict__ cntg, float* __restrict__ invg,
        int* __restrict__ colg,
        const unsigned short* __restrict__ WB1, const float* __restrict__ b1,
        const unsigned short* __restrict__ WB2, const float* __restrict__ b2,
        unsigned* __restrict__ p2, unsigned short* __restrict__ selfpb, int N) {
    __shared__ unsigned short sh[64][136];        // A-tile -> h-tile -> f32 stage
    __shared__ __align__(16) int col_l[COLCAP];   // per-node edge lists (padded x8)
    __shared__ int scnt[64], sbase[64], scur[64];
    __shared__ int stot;
    int t = threadIdx.x;
    int b = blockIdx.x;
    int cb = b >> 1, sub = b & 1;
    int cnt_b = bend[cb];                         // coarse bucket edge count
    size_t ebeg = (size_t)cb * CAP_C;

    // ---- sort phase: register-cached single scan of the coarse segment ----
    int ec[KE2];
#pragma unroll
    for (int j = 0; j < KE2; j++) {
        int i = t + j * 256;
        ec[j] = (i < cnt_b) ? eb[ebeg + i] : -1;
    }
    if (t < 64) scnt[t] = 0;
    __syncthreads();
#pragma unroll
    for (int j = 0; j < KE2; j++) {
        int pk = ec[j];
        if (pk >= 0) {
            int loc = pk >> 17;                   // 7 bits: 0..127
            if ((loc >> 6) == sub) atomicAdd(&scnt[loc & 63], 1);
        }
    }
    __syncthreads();
    if (t < 64) {                                 // wave 0: shuffle prefix scan
        int c = scnt[t];
        int pc = (c + 7) & ~7;                    // pad to x8 (agg2 reads 8-wide)
        int scan = pc;
#pragma unroll
        for (int off = 1; off < 64; off <<= 1) {
            int u = __shfl_up(scan, off);
            if (t >= off) scan += u;
        }
        int base = scan - pc;
        sbase[t] = base;
        scur[t] = base;
        if (t == 63) stot = scan;
        int node = b * 64 + t;
        if (node < N) {
            rowptr[node] = b * COLCAP + base;
            cntg[node] = c;
            invg[node] = 1.0f / (float)(c > 0 ? c : 1);
        }
    }
    __syncthreads();
#pragma unroll
    for (int j = 0; j < KE2; j++) {
        int pk = ec[j];
        if (pk >= 0) {
            int loc = pk >> 17;
            if ((loc >> 6) == sub) {
                int pos = atomicAdd(&scur[loc & 63], 1);
                col_l[pos] = pk & 0x1FFFF;
            }
        }
    }
    __syncthreads();
    if (t < 64) {
        int c = scnt[t], pc = (c + 7) & ~7, base = sbase[t];
        for (int i = c; i < pc; i++) col_l[base + i] = NN;   // pads -> zero dummy row
    }
    __syncthreads();
    {   // coalesced copy for agg2 (col_l is final; Phase A also reads it below)
        int tot = stot;
        for (int i = t; i < tot; i += 256)
            colg[(size_t)b * COLCAP + i] = col_l[i];
    }

    // ---- Phase A: aggregate wave-private rows (fp8 gather, col from LDS) ----
    int w = t >> 6, lane = t & 63;
    int lw = w * 16;
    int g8 = (t >> 3) & 7;                   // gather group within wave: 0..7
    int chunk = t & 7;                       // 8B fp8 chunk within row
    int rbase = b * 64 + lw;
#pragma unroll
    for (int it = 0; it < 2; ++it) {
        int lr = lw + g8 + it * 8;
        int n = b * 64 + lr;
        bool valid = (n < N);
        int ne = valid ? n : NN;             // NN = zero dummy row
        float a[8];
#pragma unroll
        for (int j = 0; j < 8; j++) a[j] = 0.f;
        float invn = 0.f;
        if (valid) {
            int beg = sbase[lr], deg = scnt[lr];
            int degp = (deg + 3) & ~3;
            for (int i = 0; i < degp; i += 4) {
                int4 c4 = *(const int4*)(col_l + beg + i);
                uint2 g0 = *(const uint2*)(xgs + (size_t)c4.x * 32 + chunk * 4);
                uint2 g1 = *(const uint2*)(xgs + (size_t)c4.y * 32 + chunk * 4);
                uint2 g2 = *(const uint2*)(xgs + (size_t)c4.z * 32 + chunk * 4);
                uint2 g3 = *(const uint2*)(xgs + (size_t)c4.w * 32 + chunk * 4);
                f32x2 d;
                d = __builtin_amdgcn_cvt_pk_f32_fp8(g0.x, false); a[0] += d.x; a[1] += d.y;
                d = __builtin_amdgcn_cvt_pk_f32_fp8(g0.x, true);  a[2] += d.x; a[3] += d.y;
                d = __builtin_amdgcn_cvt_pk_f32_fp8(g0.y, false); a[4] += d.x; a[5] += d.y;
                d = __builtin_amdgcn_cvt_pk_f32_fp8(g0.y, true);  a[6] += d.x; a[7] += d.y;
                d = __builtin_amdgcn_cvt_pk_f32_fp8(g1.x, false); a[0] += d.x; a[1] += d.y;
                d = __builtin_amdgcn_cvt_pk_f32_fp8(g1.x, true);  a[2] += d.x; a[3] += d.y;
                d = __builtin_amdgcn_cvt_pk_f32_fp8(g1.y, false); a[4] += d.x; a[5] += d.y;
                d = __builtin_amdgcn_cvt_pk_f32_fp8(g1.y, true);  a[6] += d.x; a[7] += d.y;
                d = __builtin_amdgcn_cvt_pk_f32_fp8(g2.x, false); a[0] += d.x; a[1] += d.y;
                d = __builtin_amdgcn_cvt_pk_f32_fp8(g2.x, true);  a[2] += d.x; a[3] += d.y;
                d = __builtin_amdgcn_cvt_pk_f32_fp8(g2.y, false); a[4] += d.x; a[5] += d.y;
                d = __builtin_amdgcn_cvt_pk_f32_fp8(g2.y, true);  a[6] += d.x; a[7] += d.y;
                d = __builtin_amdgcn_cvt_pk_f32_fp8(g3.x, false); a[0] += d.x; a[1] += d.y;
                d = __builtin_amdgcn_cvt_pk_f32_fp8(g3.x, true);  a[2] += d.x; a[3] += d.y;
                d = __builtin_amdgcn_cvt_pk_f32_fp8(g3.y, false); a[4] += d.x; a[5] += d.y;
                d = __builtin_amdgcn_cvt_pk_f32_fp8(g3.y, true);  a[6] += d.x; a[7] += d.y;
            }
            invn = 1.0f / (float)(deg > 0 ? deg : 1);
        }
        // self features stay bf16 (exact path)
        uint4 u = *(const uint4*)(xb + (size_t)ne * 32 + chunk * 4);
        uint4 o;
        o.x = bf16pair(a[0] * invn, a[1] * invn);
        o.y = bf16pair(a[2] * invn, a[3] * invn);
        o.z = bf16pair(a[4] * invn, a[5] * invn);
        o.w = bf16pair(a[6] * invn, a[7] * invn);
        *(uint4*)&sh[lr][chunk * 8] = o;        // agg half (cols 0..63)
        *(uint4*)&sh[lr][64 + chunk * 8] = u;   // self half (cols 64..127)
    }
    asm volatile("" ::: "memory");

    // ---- Phase B: GEMM1 (reads/writes only own rows) ----
    int quad = lane >> 4, m = lane & 15;
    f32x4 acc[8];
#pragma unroll
    for (int nt = 0; nt < 8; nt++) acc[nt] = (f32x4)(0.f);
#pragma unroll
    for (int ks = 0; ks < 4; ks++) {
        bf16x8 a = *(const bf16x8*)(&sh[lw + m][ks * 32 + quad * 8]);
#pragma unroll
        for (int nt = 0; nt < 8; nt++) {
            bf16x8 bb = *(const bf16x8*)(WB1 + ((size_t)(nt * 4 + ks) * 64 + lane) * 8);
            acc[nt] = __builtin_amdgcn_mfma_f32_16x16x32_bf16(a, bb, acc[nt], 0, 0, 0);
        }
    }
    asm volatile("" ::: "memory");
#pragma unroll
    for (int nt = 0; nt < 8; nt++) {
        int colj = nt * 16 + m;
        float bj = b1[colj];
#pragma unroll
        for (int r = 0; r < 4; r++) {
            sh[lw + quad * 4 + r][colj] = bf16r(fmaxf(acc[nt][r] + bj, 0.f));
        }
    }
    asm volatile("" ::: "memory");

    // ---- Phase C: GEMM2 ----
    f32x4 acc2[5];
#pragma unroll
    for (int nt = 0; nt < 5; nt++) acc2[nt] = (f32x4)(0.f);
#pragma unroll
    for (int ks = 0; ks < 4; ks++) {
        bf16x8 a = *(const bf16x8*)(&sh[lw + m][ks * 32 + quad * 8]);
#pragma unroll
        for (int nt = 0; nt < 5; nt++) {
            bf16x8 bb = *(const bf16x8*)(WB2 + ((size_t)(nt * 4 + ks) * 64 + lane) * 8);
            acc2[nt] = __builtin_amdgcn_mfma_f32_16x16x32_bf16(a, bb, acc2[nt], 0, 0, 0);
        }
    }
    asm volatile("" ::: "memory");
    float* stw = (float*)&sh[lw][0];         // 16 rows x 41 f32 = 2624 B <= 4352 B
#pragma unroll
    for (int nt = 0; nt < 5; nt++) {
        int colj = nt * 16 + m;
#pragma unroll
        for (int r = 0; r < 4; r++) {
            int row = rbase + quad * 4 + r;
            float v = acc2[nt][r];
            if (colj < 40) {
                stw[(quad * 4 + r) * 41 + colj] = v;
            } else if (row < N) {
                selfpb[(size_t)row * 40 + (colj - 40)] = bf16r(v + b2[colj - 40]);
            }
        }
    }
    asm volatile("" ::: "memory");
    for (int i = lane; i < 160; i += 64) {
        int lr = i / 10, dw = i - lr * 10;
        int grow = rbase + lr;
        if (grow < N) {
            float v0 = stw[lr * 41 + dw * 4 + 0], v1 = stw[lr * 41 + dw * 4 + 1];
            float v2 = stw[lr * 41 + dw * 4 + 2], v3 = stw[lr * 41 + dw * 4 + 3];
            unsigned u = __builtin_amdgcn_cvt_pk_fp8_f32(v0, v1, 0u, false);
            u = __builtin_amdgcn_cvt_pk_fp8_f32(v2, v3, u, true);
            p2[(size_t)grow * P2S + dw] = u;
        }
    }
}

// ---------- agg2 + log_softmax: 8 lanes/node (5 active), edges 8-wide ----------
// p2 rows now 64B-aligned single-line: each edge gather touches exactly 1 line.
__global__ void agg2_softmax_kernel(const unsigned* __restrict__ p2,
                                    const unsigned short* __restrict__ selfpb,
                                    const int* __restrict__ rowptr,
                                    const int* __restrict__ cnt,
                                    const float* __restrict__ inv,
                                    const int* __restrict__ col,
                                    float* __restrict__ out, int N) {
    int n = (blockIdx.x * 256 + threadIdx.x) >> 3;
    int chunk = threadIdx.x & 7;
    if (n >= N) return;
    int beg = rowptr[n], deg = cnt[n];
    int degp = (deg + 7) & ~7;
    bool vc = (chunk < 5);
    float a[8];
#pragma unroll
    for (int j = 0; j < 8; j++) a[j] = 0.f;
    for (int i = 0; i < degp; i += 8) {
        int ss[8];
#pragma unroll
        for (int k = 0; k < 8; k++) ss[k] = col[beg + i + k];
        if (vc) {
            uint2 uu[8];
#pragma unroll
            for (int k = 0; k < 8; k++)
                uu[k] = *(const uint2*)(p2 + (size_t)ss[k] * P2S + chunk * 2);
#pragma unroll
            for (int k = 0; k < 8; k++) {
                f32x2 d;
                d = __builtin_amdgcn_cvt_pk_f32_fp8(uu[k].x, false); a[0] += d.x; a[1] += d.y;
                d = __builtin_amdgcn_cvt_pk_f32_fp8(uu[k].x, true);  a[2] += d.x; a[3] += d.y;
                d = __builtin_amdgcn_cvt_pk_f32_fp8(uu[k].y, false); a[4] += d.x; a[5] += d.y;
                d = __builtin_amdgcn_cvt_pk_f32_fp8(uu[k].y, true);  a[6] += d.x; a[7] += d.y;
            }
        }
    }
    float invn = inv[n];
    float v[8];
    if (vc) {
        uint4 sv = *(const uint4*)(selfpb + (size_t)n * 40 + chunk * 8);
        v[0] = a[0] * invn + bflo(sv.x); v[1] = a[1] * invn + bfhi(sv.x);
        v[2] = a[2] * invn + bflo(sv.y); v[3] = a[3] * invn + bfhi(sv.y);
        v[4] = a[4] * invn + bflo(sv.z); v[5] = a[5] * invn + bfhi(sv.z);
        v[6] = a[6] * invn + bflo(sv.w); v[7] = a[7] * invn + bfhi(sv.w);
    } else {
#pragma unroll
        for (int j = 0; j < 8; j++) v[j] = 0.f;
    }
    float mv = -INFINITY;
    if (vc) {
#pragma unroll
        for (int j = 0; j < 8; j++) mv = fmaxf(mv, v[j]);
    }
#pragma unroll
    for (int off = 1; off <= 4; off <<= 1) mv = fmaxf(mv, __shfl_xor(mv, off, 8));
    float es = 0.f;
    if (vc) {
#pragma unroll
        for (int j = 0; j < 8; j++) es += expf(v[j] - mv);
    }
#pragma unroll
    for (int off = 1; off <= 4; off <<= 1) es += __shfl_xor(es, off, 8);
    if (vc) {
        float ls = mv + logf(es);
        float4 o0, o1;
        o0.x = v[0] - ls; o0.y = v[1] - ls; o0.z = v[2] - ls; o0.w = v[3] - ls;
        o1.x = v[4] - ls; o1.y = v[5] - ls; o1.z = v[6] - ls; o1.w = v[7] - ls;
        *(float4*)(out + (size_t)n * DO + chunk * 8) = o0;
        *(float4*)(out + (size_t)n * DO + chunk * 8 + 4) = o1;
    }
}

extern "C" void kernel_launch(void* const* d_in, const int* in_sizes, int n_in,
                              void* d_out, int out_size, void* d_ws, size_t ws_size,
                              hipStream_t stream) {
    const float* x   = (const float*)d_in[0];
    const int*  ei   = (const int*)d_in[1];
    const float* W1l = (const float*)d_in[2];
    const float* b1  = (const float*)d_in[3];
    const float* W1r = (const float*)d_in[4];
    const float* W2l = (const float*)d_in[5];
    const float* b2  = (const float*)d_in[6];
    const float* W2r = (const float*)d_in[7];
    float* out = (float*)d_out;

    const int E = in_sizes[1] / 2;
    const int N = NN;
    const int* src = ei;
    const int* dst = ei + E;
    const int nbe = (E + EPB - 1) / EPB;
    const int nsetup = ((N + 1) * 32 + TPB_S - 1) / TPB_S;
    const int nagg = (N + 63) / 64;    // 1563 agg blocks = 2 per coarse bucket

    size_t off = 0;
    auto alloc = [&](size_t nf) { size_t o = off; off += (nf + 63) & ~(size_t)63; return o; };
    size_t o_bcur   = alloc(NBUCK_C);                     // int (counts, memset to 0)
    size_t o_eb     = alloc((size_t)NBUCK_C * CAP_C);     // int (coarse-clustered edges)
    size_t o_colg   = alloc((size_t)nagg * COLCAP + 64);  // int (padded CSR col, for agg2)
    size_t o_rowptr = alloc(N);                           // int
    size_t o_cnt    = alloc(N);                           // int
    size_t o_inv    = alloc(N);                           // f32
    size_t o_xb     = alloc((size_t)(N + 1) * 32);        // u32 (64 bf16/row, +dummy)
    size_t o_xg     = alloc((size_t)(N + 1) * 16);        // fp8 x64/row = 64B (+dummy)
    size_t o_p2     = alloc((size_t)(N + 1) * P2S);       // u32 x16/row = 64B (padded, +dummy)
    size_t o_selfp  = alloc((size_t)N * 20);              // bf16 x40/row = 80B
    size_t o_wb1    = alloc(16384 / 2);
    size_t o_wb2    = alloc(10240 / 2);
    (void)ws_size;

    float* ws = (float*)d_ws;
    int* bcur   = (int*)(ws + o_bcur);
    int* eb     = (int*)(ws + o_eb);
    int* colg   = (int*)(ws + o_colg);
    int* rowptr = (int*)(ws + o_rowptr);
    int* cnt    = (int*)(ws + o_cnt);
    float* inv  = ws + o_inv;
    unsigned* xb = (unsigned*)(ws + o_xb);
    unsigned short* xgs = (unsigned short*)(ws + o_xg);
    unsigned* p2 = (unsigned*)(ws + o_p2);
    unsigned short* selfpb = (unsigned short*)(ws + o_selfp);
    unsigned short* WB1 = (unsigned short*)(ws + o_wb1);
    unsigned short* WB2 = (unsigned short*)(ws + o_wb2);

    hipMemsetAsync(bcur, 0, NBUCK_C * sizeof(int), stream);

    setup_scatter_kernel<<<nbe + nsetup, TPB_S, 0, stream>>>(
        x, W1l, W1r, W2l, W2r, xb, xgs, WB1, WB2, p2, src, dst, bcur, eb, nbe, E, N);

    agg_gemm12_kernel<<<nagg, 256, 0, stream>>>(
        xb, xgs, eb, bcur, rowptr, cnt, inv, colg,
        WB1, b1, WB2, b2, p2, selfpb, N);

    agg2_softmax_kernel<<<(N * 8 + 255) / 256, 256, 0, stream>>>(
        p2, selfpb, rowptr, cnt, inv, colg, out, N);
}